// Round 6
// baseline (343.002 us; speedup 1.0000x reference)
//
#include <hip/hip_runtime.h>
#include <math.h>

#define EPSF 1e-6f
#define NB   4
#define NC   3
#define HH   768
#define KS   31
#define KK   961
#define NHW  11
#define NN   121
#define NZ   14
#define HID  64

// workspace layout (float offsets). xlin stored as f16 (u16).
#define XLIN_OFF  0
#define XLIN_F    3538944                  // 7,077,888 u16 = 3,538,944 floats
#define BASIS_OFF (XLIN_OFF + XLIN_F)
#define MASK_OFF  (BASIS_OFF + 13456)      // basis 14*961=13454
#define COEF_OFF  (MASK_OFF + 964)         // mask 961
#define KERN_OFF  (COEF_OFF + 1696)        // f16x8 window tap tables (R11)
#define WNC_U4    (31 * 96)                // 2976 uint4 per (n,c) = 47.6 KB
// total ws ~31.5 MB

typedef _Float16 h8 __attribute__((ext_vector_type(8)));
typedef float f32x16 __attribute__((ext_vector_type(16)));

__device__ __forceinline__ unsigned pack_h2(float a, float b) {
    return __builtin_bit_cast(unsigned, __builtin_amdgcn_cvt_pkrtz(a, b));
}

__device__ __forceinline__ float hann_f(int p) {
    return 0.5f * (1.0f - cosf(6.283185307179586f * (float)p / 128.0f));
}

// async global->LDS, 16B per active lane; dst = uniform base + lane*16.
__device__ __forceinline__ void gll16(const uint4* g, uint4* l) {
    __builtin_amdgcn_global_load_lds(
        (const __attribute__((address_space(1))) unsigned*)g,
        (__attribute__((address_space(3))) unsigned*)l,
        16, 0, 0);
}

// R13: vectorized (float4 -> 4 f16); n divisible by 4.
__global__ void k_pow(const float4* __restrict__ x, const float* __restrict__ gp,
                      uint2* __restrict__ y, int n4) {
    float g = *gp;
    for (int i = blockIdx.x * blockDim.x + threadIdx.x; i < n4; i += gridDim.x * blockDim.x) {
        float4 v = x[i];
        uint2 o;
        o.x = pack_h2(__powf(fmaxf(v.x, 0.0f) + EPSF, g), __powf(fmaxf(v.y, 0.0f) + EPSF, g));
        o.y = pack_h2(__powf(fmaxf(v.z, 0.0f) + EPSF, g), __powf(fmaxf(v.w, 0.0f) + EPSF, g));
        y[i] = o;
    }
}

// Zernike-like polynomial basis, bit-exact mask vs numpy linspace semantics.
__global__ void k_basis(float* __restrict__ ws) {
    __shared__ float red[256];
    __shared__ float srms[NZ];
    __shared__ float scnt;
    float* basis = ws + BASIS_OFF;
    float* mask  = ws + MASK_OFF;
    int tid = threadIdx.x;
    double lsq[NZ];
    #pragma unroll
    for (int z = 0; z < NZ; ++z) lsq[z] = 0.0;
    double lcnt = 0.0;
    for (int pix = tid; pix < KK; pix += 256) {
        int i = pix / 31, j = pix - i * 31;
        double x = (j == 30) ? 1.0 : (-1.0 + (double)j * (2.0 / 30.0));
        double y = (i == 30) ? 1.0 : (-1.0 + (double)i * (2.0 / 30.0));
        double r2 = x * x + y * y;
        float m = (r2 <= 1.0) ? 1.0f : 0.0f;
        mask[pix] = m;
        lcnt += (double)m;
        #pragma unroll
        for (int deg = 1; deg <= 4; ++deg) {
            #pragma unroll
            for (int ii = 0; ii <= deg; ++ii) {
                const int z = deg * (deg + 1) / 2 - 1 + ii;
                double px = 1.0, py = 1.0;
                #pragma unroll
                for (int t = 0; t < deg - ii; ++t) px *= x;
                #pragma unroll
                for (int t = 0; t < ii; ++t) py *= y;
                float bf = (float)(px * py) * m;
                basis[z * KK + pix] = bf;
                lsq[z] += (double)bf * (double)bf;
            }
        }
    }
    for (int q = 0; q < NZ + 1; ++q) {
        red[tid] = (q < NZ) ? (float)lsq[q] : (float)lcnt;
        __syncthreads();
        for (int s = 128; s > 0; s >>= 1) {
            if (tid < s) red[tid] += red[tid + s];
            __syncthreads();
        }
        if (tid == 0) { if (q < NZ) srms[q] = red[0]; else scnt = red[0]; }
        __syncthreads();
    }
    if (tid < NZ) srms[tid] = sqrtf(srms[tid] / scnt) + 1e-8f;
    __syncthreads();
    for (int pix = tid; pix < KK; pix += 256) {
        #pragma unroll
        for (int z = 0; z < NZ; ++z)
            basis[z * KK + pix] = basis[z * KK + pix] / srms[z];
    }
}

// 121 unique coords (batch-tiled in reference), one block of 64 per coord.
__global__ void k_mlp(const float* __restrict__ w1, const float* __restrict__ b1,
                      const float* __restrict__ w2, const float* __restrict__ b2,
                      const float* __restrict__ w3, const float* __restrict__ b3,
                      float* __restrict__ ws) {
    __shared__ float h1[HID], h2v[HID];
    int n = blockIdx.x, t = threadIdx.x;
    int a = n / NHW, bw = n - a * NHW;
    float gy = (float)((((double)(a * 64)  + 64.0) / 768.0) * 2.0 - 1.0);
    float gx = (float)((((double)(bw * 64) + 64.0) / 768.0) * 2.0 - 1.0);
    h1[t] = tanhf(gy * w1[t] + gx * w1[HID + t] + b1[t]);
    __syncthreads();
    float acc2 = b2[t];
    for (int k = 0; k < HID; ++k) acc2 += h1[k] * w2[k * HID + t];
    h2v[t] = tanhf(acc2);
    __syncthreads();
    if (t < NZ) {
        float acc3 = b3[t];
        for (int k = 0; k < HID; ++k) acc3 += h2v[k] * w3[k * NZ + t];
        ws[COEF_OFF + n * NZ + t] = acc3;
    }
}

// One block per (n,c): phase -> field -> 31-pt row DFT -> col DFT -> |F|^2,
// normalize; fftshift+flip folded. Output (R11): per-v WINDOW tables —
// W[v][s] = f16x8 (Kcolpad[s..s+7]), s in [0,96), 16B-aligned rows.
// Kcolpad position x holds tap t=x-31 (t valid in [0,31)), so an MFMA
// A-fragment starting at position tA is exactly the 16B row W[v][tA].
__global__ void k_psf(float* __restrict__ ws) {
    __shared__ float fre[KK], fim[KK], gre[KK], gim[KK], sS[KK];
    __shared__ float twc[KS], tws[KS], cf[NZ], red[128];
    __shared__ float pc[31 * 104];   // padded tap columns, all v
    int blk = blockIdx.x;
    int n = blk / 3, c = blk - n * 3;
    int tid = threadIdx.x;
    const float* basis = ws + BASIS_OFF;
    const float* mask  = ws + MASK_OFF;
    if (tid < NZ) cf[tid] = ws[COEF_OFF + n * NZ + tid];
    if (tid < KS) {
        float ang = -6.283185307179586f * (float)tid / 31.0f;
        float s, co;
        sincosf(ang, &s, &co);
        twc[tid] = co; tws[tid] = s;
    }
    const float wl = (c == 0) ? (0.53f / 0.61f) : ((c == 1) ? 1.0f : (0.53f / 0.47f));
    __syncthreads();
    for (int pix = tid; pix < KK; pix += 128) {
        float ph = 0.0f;
        #pragma unroll
        for (int z = 0; z < NZ; ++z) ph += cf[z] * basis[z * KK + pix];
        float ang = 6.283185307179586f * (wl * ph);
        float s, co;
        sincosf(ang, &s, &co);
        float m = mask[pix];
        fre[pix] = m * co;
        fim[pix] = m * s;
    }
    __syncthreads();
    for (int pix = tid; pix < KK; pix += 128) {
        int i = pix / 31, q = pix - i * 31;
        float ar = 0.0f, ai = 0.0f;
        int m = 0;
        const float* br = &fre[i * 31];
        const float* bi = &fim[i * 31];
        #pragma unroll
        for (int j = 0; j < 31; ++j) {
            float tc = twc[m], ts = tws[m];
            float xr = br[j], xi = bi[j];
            ar += xr * tc - xi * ts;
            ai += xr * ts + xi * tc;
            m += q; if (m >= 31) m -= 31;
        }
        gre[pix] = ar; gim[pix] = ai;
    }
    __syncthreads();
    float lsum = 0.0f;
    for (int pix = tid; pix < KK; pix += 128) {
        int p = pix / 31, q = pix - p * 31;
        float ar = 0.0f, ai = 0.0f;
        int m = 0;
        #pragma unroll
        for (int i2 = 0; i2 < 31; ++i2) {
            float tc = twc[m], ts = tws[m];
            float xr = gre[i2 * 31 + q], xi = gim[i2 * 31 + q];
            ar += xr * tc - xi * ts;
            ai += xr * ts + xi * tc;
            m += p; if (m >= 31) m -= 31;
        }
        float sv = ar * ar + ai * ai;
        sS[pix] = sv;
        lsum += sv;
    }
    red[tid] = lsum;
    __syncthreads();
    for (int s = 64; s > 0; s >>= 1) {
        if (tid < s) red[tid] += red[tid + s];
        __syncthreads();
    }
    float tot = red[0] + EPSF;
    // build padded tap columns pc[v][x]: position x holds tap t=x-31
    // (fftshift + flip folded exactly as before; identical float values).
    for (int idx = tid; idx < 31 * 104; idx += 128) {
        int v = idx / 104, x = idx - v * 104;
        int iv = 15 - v; if (iv < 0) iv += 31;
        float val = 0.0f;
        int t = x - 31;
        if ((unsigned)t < 31u) {
            int iu = 15 - t; if (iu < 0) iu += 31;
            val = sS[iu * 31 + iv] / tot;
        }
        pc[idx] = val;
    }
    __syncthreads();
    // emit window rows: W[v][s] = f16x8(pc[v][s..s+7]); pkrtz rounds each
    // half independently -> f16 values identical to the old parity packing.
    uint4* wp = (uint4*)(ws + KERN_OFF) + (size_t)(n * 3 + c) * WNC_U4;
    for (int idx = tid; idx < 31 * 96; idx += 128) {
        int v = idx / 96, s = idx - v * 96;
        const float* p = &pc[v * 104 + s];
        uint4 u;
        u.x = pack_h2(p[0], p[1]);
        u.y = pack_h2(p[2], p[3]);
        u.z = pack_h2(p[4], p[5]);
        u.w = pack_h2(p[6], p[7]);
        wp[idx] = u;
    }
}

// Hot kernel, R16: FULLY UNROLLED v-loop. With v and buf=v&1 compile-time,
// every ds_read address folds to one loop-invariant VGPR base + 16-bit
// immediate offset (A: ((buf*4+p)*88+o*16)*16 <= 10.9KB; B: v*208+o*32
// <= 6.3KB), and gll source advances by SALU adds. R15's per-iter VALU
// address re-derivation (runtime buf/v under "unroll 1") was ~half of
// VALUBusy=47%; this collapses inner-loop VALU to ~0 and leaves the LDS
// pipe (~80 b128 per block-iter) as the binding resource.
__global__ __launch_bounds__(256, 5) void k_conv(const float* __restrict__ ws,
                                                 const float* __restrict__ gp,
                                                 float* __restrict__ out) {
    __shared__ unsigned short sT[94 * 104];   // col-major sT[col*104+q], 19.6 KB
    __shared__ uint4 At[2][4][88];            // double-buffered A slices, 11.3 KB
    int bid = blockIdx.x;
    int swz = (bid & 7) * 216 + (bid >> 3);   // XCD-contiguous chunks
    int bc = swz % 12;             // b*3+c (fastest: table sharing)
    int tile = swz / 12;
    int c = bc % 3;
    int tx = tile % 12, ta = tile / 12;
    int y0 = ta * 64, x0 = tx * 64;
    int tid = threadIdx.x;
    const unsigned short* xlc = (const unsigned short*)ws + (size_t)bc * (HH * HH);
    // stage: sT[col][q] = xlin[y0+q-15, x0+col-15], zero outside; q in [94,96)=0
    for (int idx = tid; idx < 94 * 96; idx += 256) {
        int q = idx / 94, col = idx - (idx / 94) * 94;
        int pi = y0 + q - 15, pj = x0 + col - 15;
        unsigned short hv = 0;
        if (q < 94 && (unsigned)pi < 768u && (unsigned)pj < 768u)
            hv = xlc[pi * HH + pj];
        sT[col * 104 + q] = hv;
    }
    int lane = tid & 63, wave = tid >> 6;
    int qy = wave >> 1, qx = wave & 1;    // quadrant
    int nI = lane & 31, k8 = lane >> 5;
    int cx = qx * 32 + nI;                // output col within tile
    bool vy0 = (ta <= 10), vy1 = (ta >= 1);
    bool vx0 = (tx <= 10), vx1 = (tx >= 1);
    const uint4* wtab = (const uint4*)(ws + KERN_OFF);
    // wave w stages table p=w (clamped to a real table when invalid; the
    // contribution is zeroed exactly in the epilogue weights).
    int aaw = ta - (wave >> 1), bbw = tx - (wave & 1);
    bool vw = ((unsigned)aaw < 11u) && ((unsigned)bbw < 11u);
    int nnw = vw ? (aaw * NHW + bbw) : 0;
    const uint4* stab = wtab + (size_t)(nnw * 3 + c) * WNC_U4;   // wave-uniform
    // prologue: stage v=0 into buffer 0 (rows 0..87 only)
    gll16(stab + lane, &At[0][wave][0]);
    if (lane < 24) gll16(stab + 64 + lane, &At[0][wave][64]);
    __syncthreads();              // drains vmcnt: sT + At[0] ready

    int tA0 = 8 * k8 - nI + 31;   // per-lane A row base, in [0, 39]
    // loop-invariant LDS bases; all per-read offsets are compile-time imm
    const uint4* aB = &At[0][0][0] + tA0;
    const unsigned short* bB = &sT[cx * 104 + qy * 32 + k8 * 8];
    f32x16 acc[4];
    #pragma unroll
    for (int p = 0; p < 4; ++p) acc[p] = (f32x16)(0.0f);
    #pragma unroll
    for (int v = 0; v < 31; ++v) {
        const int b = v & 1;      // compile-time under full unroll
        // stage v+1 into the other buffer (2 async issues per wave)
        if (v < 30) {
            const uint4* src = stab + (v + 1) * 96;
            gll16(src + lane, &At[b ^ 1][wave][0]);
            if (lane < 24) gll16(src + 64 + lane, &At[b ^ 1][wave][64]);
        }
        // B fragments: aligned ds_read_b128 at imm offset v*208 + o*32
        h8 B[4];
        #pragma unroll
        for (int o = 0; o < 4; ++o)
            B[o] = __builtin_bit_cast(h8, *(const uint4*)(bB + v * 104 + o * 16));
        // A fragments at imm offset ((b*4+p)*88 + o*16)*16 off aB
        #pragma unroll
        for (int p = 0; p < 4; ++p) {
            #pragma unroll
            for (int o = 0; o < 4; ++o) {
                uint4 u = aB[(b * 4 + p) * 88 + o * 16];     // ds_read_b128
                acc[p] = __builtin_amdgcn_mfma_f32_32x32x16_f16(
                    __builtin_bit_cast(h8, u), B[o], acc[p], 0, 0, 0);
            }
        }
        __syncthreads();          // At[b^1] staged; At[b] reads done
    }
    // epilogue: window + separable norm + inverse gamma, coalesced stores
    float ig = 1.0f / (*gp);
    float wxc0 = vx0 ? hann_f(cx) : 0.0f;
    float wxc1 = vx1 ? hann_f(cx + 64) : 0.0f;
    float sw = wxc0 + wxc1;
    float* ob = out + (size_t)bc * (HH * HH) + (size_t)y0 * HH + x0;
    #pragma unroll
    for (int reg = 0; reg < 16; ++reg) {
        int rr = (reg & 3) + 8 * (reg >> 2) + 4 * k8;   // row in 32x32 tile
        int ry = qy * 32 + rr;
        float wy0 = vy0 ? hann_f(ry) : 0.0f;
        float wy1 = vy1 ? hann_f(ry + 64) : 0.0f;
        float val = wy0 * (wxc0 * acc[0][reg] + wxc1 * acc[1][reg])
                  + wy1 * (wxc0 * acc[2][reg] + wxc1 * acc[3][reg]);
        float vv = val / ((wy0 + wy1) * sw + EPSF);
        ob[(size_t)ry * HH + cx] = __powf(fmaxf(vv, 0.0f) + EPSF, ig);
    }
}

extern "C" void kernel_launch(void* const* d_in, const int* in_sizes, int n_in,
                              void* d_out, int out_size, void* d_ws, size_t ws_size,
                              hipStream_t stream) {
    const float* x  = (const float*)d_in[0];
    const float* w1 = (const float*)d_in[1];
    const float* b1 = (const float*)d_in[2];
    const float* w2 = (const float*)d_in[3];
    const float* b2 = (const float*)d_in[4];
    const float* w3 = (const float*)d_in[5];
    const float* b3 = (const float*)d_in[6];
    const float* gp = (const float*)d_in[7];
    float* out = (float*)d_out;
    float* ws  = (float*)d_ws;

    int ntot = NB * NC * HH * HH;
    k_pow<<<2048, 256, 0, stream>>>((const float4*)x, gp, (uint2*)(ws + XLIN_OFF), ntot / 4);
    k_basis<<<1, 256, 0, stream>>>(ws);
    k_mlp<<<NN, 64, 0, stream>>>(w1, b1, w2, b2, w3, b3, ws);
    k_psf<<<NN * NC, 128, 0, stream>>>(ws);
    k_conv<<<NB * NC * 144, 256, 0, stream>>>(ws, gp, out);
}

// Round 8
// 281.592 us; speedup vs baseline: 1.2181x; 1.2181x over previous
//
#include <hip/hip_runtime.h>
#include <math.h>

#define EPSF 1e-6f
#define NB   4
#define NC   3
#define HH   768
#define KS   31
#define KK   961
#define NHW  11
#define NN   121
#define NZ   14
#define HID  64

// workspace layout (float offsets). xlin stored as f16 (u16).
#define XLIN_OFF  0
#define XLIN_F    3538944                  // 7,077,888 u16 = 3,538,944 floats
#define BASIS_OFF (XLIN_OFF + XLIN_F)
#define MASK_OFF  (BASIS_OFF + 13456)      // basis 14*961=13454
#define COEF_OFF  (MASK_OFF + 964)         // mask 961
#define KERN_OFF  (COEF_OFF + 1696)        // f16x8 window tap tables (R11)
#define WNC_U4    (31 * 96)                // 2976 uint4 per (n,c) = 47.6 KB
// total ws ~31.5 MB

typedef _Float16 h8 __attribute__((ext_vector_type(8)));
typedef float f32x16 __attribute__((ext_vector_type(16)));

__device__ __forceinline__ unsigned pack_h2(float a, float b) {
    return __builtin_bit_cast(unsigned, __builtin_amdgcn_cvt_pkrtz(a, b));
}

__device__ __forceinline__ float hann_f(int p) {
    return 0.5f * (1.0f - cosf(6.283185307179586f * (float)p / 128.0f));
}

// async global->LDS, 16B per active lane; dst = uniform base + lane*16.
__device__ __forceinline__ void gll16(const uint4* g, uint4* l) {
    __builtin_amdgcn_global_load_lds(
        (const __attribute__((address_space(1))) unsigned*)g,
        (__attribute__((address_space(3))) unsigned*)l,
        16, 0, 0);
}

// R17 front fusion: one launch does mlp (blocks 0..120), basis (block 121),
// and pow (blocks 122+). mlp/basis bodies are numerically IDENTICAL to the
// previous separate kernels (same thread counts in the reduction trees).
__global__ void k_front(const float4* __restrict__ x, const float* __restrict__ gp,
                        uint2* __restrict__ y, int n4,
                        const float* __restrict__ w1, const float* __restrict__ b1,
                        const float* __restrict__ w2, const float* __restrict__ b2,
                        const float* __restrict__ w3, const float* __restrict__ b3,
                        float* __restrict__ ws) {
    __shared__ float h1[HID], h2v[HID];
    __shared__ float red[256];
    __shared__ float srms[NZ];
    __shared__ float scnt;
    int bid = blockIdx.x, t = threadIdx.x;
    if (bid < NN) {
        // ---- mlp for coord n=bid (t<64 compute, all-thread barriers) ----
        int n = bid;
        int a = n / NHW, bw = n - a * NHW;
        float gy = (float)((((double)(a * 64)  + 64.0) / 768.0) * 2.0 - 1.0);
        float gx = (float)((((double)(bw * 64) + 64.0) / 768.0) * 2.0 - 1.0);
        if (t < HID) h1[t] = tanhf(gy * w1[t] + gx * w1[HID + t] + b1[t]);
        __syncthreads();
        if (t < HID) {
            float acc2 = b2[t];
            for (int k = 0; k < HID; ++k) acc2 += h1[k] * w2[k * HID + t];
            h2v[t] = tanhf(acc2);
        }
        __syncthreads();
        if (t < NZ) {
            float acc3 = b3[t];
            for (int k = 0; k < HID; ++k) acc3 += h2v[k] * w3[k * NZ + t];
            ws[COEF_OFF + n * NZ + t] = acc3;
        }
        return;
    }
    if (bid == NN) {
        // ---- basis: verbatim 256-thread body (bit-identical numerics) ----
        float* basis = ws + BASIS_OFF;
        float* mask  = ws + MASK_OFF;
        int tid = t;
        double lsq[NZ];
        #pragma unroll
        for (int z = 0; z < NZ; ++z) lsq[z] = 0.0;
        double lcnt = 0.0;
        for (int pix = tid; pix < KK; pix += 256) {
            int i = pix / 31, j = pix - i * 31;
            double xx = (j == 30) ? 1.0 : (-1.0 + (double)j * (2.0 / 30.0));
            double yy = (i == 30) ? 1.0 : (-1.0 + (double)i * (2.0 / 30.0));
            double r2 = xx * xx + yy * yy;
            float m = (r2 <= 1.0) ? 1.0f : 0.0f;
            mask[pix] = m;
            lcnt += (double)m;
            #pragma unroll
            for (int deg = 1; deg <= 4; ++deg) {
                #pragma unroll
                for (int ii = 0; ii <= deg; ++ii) {
                    const int z = deg * (deg + 1) / 2 - 1 + ii;
                    double px = 1.0, py = 1.0;
                    #pragma unroll
                    for (int q = 0; q < deg - ii; ++q) px *= xx;
                    #pragma unroll
                    for (int q = 0; q < ii; ++q) py *= yy;
                    float bf = (float)(px * py) * m;
                    basis[z * KK + pix] = bf;
                    lsq[z] += (double)bf * (double)bf;
                }
            }
        }
        for (int q = 0; q < NZ + 1; ++q) {
            red[tid] = (q < NZ) ? (float)lsq[q] : (float)lcnt;
            __syncthreads();
            for (int s = 128; s > 0; s >>= 1) {
                if (tid < s) red[tid] += red[tid + s];
                __syncthreads();
            }
            if (tid == 0) { if (q < NZ) srms[q] = red[0]; else scnt = red[0]; }
            __syncthreads();
        }
        if (tid < NZ) srms[tid] = sqrtf(srms[tid] / scnt) + 1e-8f;
        __syncthreads();
        for (int pix = tid; pix < KK; pix += 256) {
            #pragma unroll
            for (int z = 0; z < NZ; ++z)
                basis[z * KK + pix] = basis[z * KK + pix] / srms[z];
        }
        return;
    }
    // ---- pow: blocks NN+1.. grid-stride over n4 float4s ----
    float g = *gp;
    int i0 = (bid - (NN + 1)) * blockDim.x + t;
    int gs = (gridDim.x - (NN + 1)) * blockDim.x;
    for (int i = i0; i < n4; i += gs) {
        float4 v = x[i];
        uint2 o;
        o.x = pack_h2(__powf(fmaxf(v.x, 0.0f) + EPSF, g), __powf(fmaxf(v.y, 0.0f) + EPSF, g));
        o.y = pack_h2(__powf(fmaxf(v.z, 0.0f) + EPSF, g), __powf(fmaxf(v.w, 0.0f) + EPSF, g));
        y[i] = o;
    }
}

// One block per (n,c): phase -> field -> 31-pt row DFT -> col DFT -> |F|^2,
// normalize; fftshift+flip folded. Output (R11): per-v WINDOW tables —
// W[v][s] = f16x8 (Kcolpad[s..s+7]), s in [0,96), 16B-aligned rows.
__global__ void k_psf(float* __restrict__ ws) {
    __shared__ float fre[KK], fim[KK], gre[KK], gim[KK], sS[KK];
    __shared__ float twc[KS], tws[KS], cf[NZ], red[128];
    __shared__ float pc[31 * 104];   // padded tap columns, all v
    int blk = blockIdx.x;
    int n = blk / 3, c = blk - n * 3;
    int tid = threadIdx.x;
    const float* basis = ws + BASIS_OFF;
    const float* mask  = ws + MASK_OFF;
    if (tid < NZ) cf[tid] = ws[COEF_OFF + n * NZ + tid];
    if (tid < KS) {
        float ang = -6.283185307179586f * (float)tid / 31.0f;
        float s, co;
        sincosf(ang, &s, &co);
        twc[tid] = co; tws[tid] = s;
    }
    const float wl = (c == 0) ? (0.53f / 0.61f) : ((c == 1) ? 1.0f : (0.53f / 0.47f));
    __syncthreads();
    for (int pix = tid; pix < KK; pix += 128) {
        float ph = 0.0f;
        #pragma unroll
        for (int z = 0; z < NZ; ++z) ph += cf[z] * basis[z * KK + pix];
        float ang = 6.283185307179586f * (wl * ph);
        float s, co;
        sincosf(ang, &s, &co);
        float m = mask[pix];
        fre[pix] = m * co;
        fim[pix] = m * s;
    }
    __syncthreads();
    for (int pix = tid; pix < KK; pix += 128) {
        int i = pix / 31, q = pix - i * 31;
        float ar = 0.0f, ai = 0.0f;
        int m = 0;
        const float* br = &fre[i * 31];
        const float* bi = &fim[i * 31];
        #pragma unroll
        for (int j = 0; j < 31; ++j) {
            float tc = twc[m], ts = tws[m];
            float xr = br[j], xi = bi[j];
            ar += xr * tc - xi * ts;
            ai += xr * ts + xi * tc;
            m += q; if (m >= 31) m -= 31;
        }
        gre[pix] = ar; gim[pix] = ai;
    }
    __syncthreads();
    float lsum = 0.0f;
    for (int pix = tid; pix < KK; pix += 128) {
        int p = pix / 31, q = pix - p * 31;
        float ar = 0.0f, ai = 0.0f;
        int m = 0;
        #pragma unroll
        for (int i2 = 0; i2 < 31; ++i2) {
            float tc = twc[m], ts = tws[m];
            float xr = gre[i2 * 31 + q], xi = gim[i2 * 31 + q];
            ar += xr * tc - xi * ts;
            ai += xr * ts + xi * tc;
            m += p; if (m >= 31) m -= 31;
        }
        float sv = ar * ar + ai * ai;
        sS[pix] = sv;
        lsum += sv;
    }
    red[tid] = lsum;
    __syncthreads();
    for (int s = 64; s > 0; s >>= 1) {
        if (tid < s) red[tid] += red[tid + s];
        __syncthreads();
    }
    float tot = red[0] + EPSF;
    for (int idx = tid; idx < 31 * 104; idx += 128) {
        int v = idx / 104, x = idx - v * 104;
        int iv = 15 - v; if (iv < 0) iv += 31;
        float val = 0.0f;
        int t = x - 31;
        if ((unsigned)t < 31u) {
            int iu = 15 - t; if (iu < 0) iu += 31;
            val = sS[iu * 31 + iv] / tot;
        }
        pc[idx] = val;
    }
    __syncthreads();
    uint4* wp = (uint4*)(ws + KERN_OFF) + (size_t)(n * 3 + c) * WNC_U4;
    for (int idx = tid; idx < 31 * 96; idx += 128) {
        int v = idx / 96, s = idx - v * 96;
        const float* p = &pc[v * 104 + s];
        uint4 u;
        u.x = pack_h2(p[0], p[1]);
        u.y = pack_h2(p[2], p[3]);
        u.z = pack_h2(p[4], p[5]);
        u.w = pack_h2(p[6], p[7]);
        wp[idx] = u;
    }
}

// Hot kernel, R17: R15 structure (best verified) + hann LDS TABLE epilogue.
// R16 proved the ~70us of VALU cycles are NOT loop addressing (they survived
// full unroll) — they were 34 libm cosf + 16 divides per thread in the
// epilogue. Fix: hT[128] table (128 cosf per BLOCK, not 8700 per block) and
// the exact identity hann(p+64) = 1 - hann(p).
__global__ __launch_bounds__(256, 5) void k_conv(const float* __restrict__ ws,
                                                 const float* __restrict__ gp,
                                                 float* __restrict__ out) {
    __shared__ unsigned short sT[94 * 104];   // col-major sT[col*104+q], 19.6 KB
    __shared__ uint4 At[2][4][88];            // double-buffered A slices, 11.3 KB
    __shared__ float hT[128];                 // hann table, 512 B
    int bid = blockIdx.x;
    int swz = (bid & 7) * 216 + (bid >> 3);   // XCD-contiguous chunks
    int bc = swz % 12;             // b*3+c (fastest: table sharing)
    int tile = swz / 12;
    int c = bc % 3;
    int tx = tile % 12, ta = tile / 12;
    int y0 = ta * 64, x0 = tx * 64;
    int tid = threadIdx.x;
    const unsigned short* xlc = (const unsigned short*)ws + (size_t)bc * (HH * HH);
    if (tid < 128) hT[tid] = hann_f(tid);
    // stage: sT[col][q] = xlin[y0+q-15, x0+col-15], zero outside; q in [94,96)=0
    for (int idx = tid; idx < 94 * 96; idx += 256) {
        int q = idx / 94, col = idx - (idx / 94) * 94;
        int pi = y0 + q - 15, pj = x0 + col - 15;
        unsigned short hv = 0;
        if (q < 94 && (unsigned)pi < 768u && (unsigned)pj < 768u)
            hv = xlc[pi * HH + pj];
        sT[col * 104 + q] = hv;
    }
    int lane = tid & 63, wave = tid >> 6;
    int qy = wave >> 1, qx = wave & 1;    // quadrant
    int nI = lane & 31, k8 = lane >> 5;
    int cx = qx * 32 + nI;                // output col within tile
    bool vy0 = (ta <= 10), vy1 = (ta >= 1);
    bool vx0 = (tx <= 10), vx1 = (tx >= 1);
    const uint4* wtab = (const uint4*)(ws + KERN_OFF);
    // wave w stages table p=w (clamped to a real table when invalid; the
    // contribution is zeroed exactly in the epilogue weights).
    int aaw = ta - (wave >> 1), bbw = tx - (wave & 1);
    bool vw = ((unsigned)aaw < 11u) && ((unsigned)bbw < 11u);
    int nnw = vw ? (aaw * NHW + bbw) : 0;
    const uint4* stab = wtab + (size_t)(nnw * 3 + c) * WNC_U4;   // wave-uniform
    // prologue: stage v=0 into buffer 0 (rows 0..87 only)
    gll16(stab + lane, &At[0][wave][0]);
    if (lane < 24) gll16(stab + 64 + lane, &At[0][wave][64]);
    __syncthreads();              // drains vmcnt: sT + At[0] + hT ready

    int tA0 = 8 * k8 - nI + 31;   // per-lane A row base, in [0, 39]
    f32x16 acc[4];
    #pragma unroll
    for (int p = 0; p < 4; ++p) acc[p] = (f32x16)(0.0f);
    int buf = 0;
    #pragma unroll 1
    for (int v = 0; v < 31; ++v) {
        // stage v+1 into the other buffer (2 async issues per wave)
        if (v < 30) {
            const uint4* src = stab + (v + 1) * 96;
            gll16(src + lane, &At[buf ^ 1][wave][0]);
            if (lane < 24) gll16(src + 64 + lane, &At[buf ^ 1][wave][64]);
        }
        // B fragments: one aligned ds_read_b128 each (no repacking)
        h8 B[4];
        const uint4* cb = (const uint4*)&sT[(cx + v) * 104 + qy * 32 + k8 * 8];
        #pragma unroll
        for (int o = 0; o < 4; ++o)
            B[o] = __builtin_bit_cast(h8, cb[o * 2]);
        // A fragments from LDS + MFMA (4 independent chains)
        #pragma unroll
        for (int p = 0; p < 4; ++p) {
            #pragma unroll
            for (int o = 0; o < 4; ++o) {
                uint4 u = At[buf][p][tA0 + o * 16];          // ds_read_b128
                h8 A = __builtin_bit_cast(h8, u);
                acc[p] = __builtin_amdgcn_mfma_f32_32x32x16_f16(
                    A, B[o], acc[p], 0, 0, 0);
            }
        }
        __syncthreads();          // At[buf^1] staged; At[buf] reads done
        buf ^= 1;
    }
    // epilogue: window + separable norm + inverse gamma, coalesced stores.
    // hann from LDS table; hann(p+64) = 1 - hann(p) exactly.
    float ig = 1.0f / (*gp);
    float hx = hT[cx];
    float wxc0 = vx0 ? hx : 0.0f;
    float wxc1 = vx1 ? (1.0f - hx) : 0.0f;
    float sw = wxc0 + wxc1;
    float* ob = out + (size_t)bc * (HH * HH) + (size_t)y0 * HH + x0;
    #pragma unroll
    for (int reg = 0; reg < 16; ++reg) {
        int rr = (reg & 3) + 8 * (reg >> 2) + 4 * k8;   // row in 32x32 tile
        int ry = qy * 32 + rr;
        float hy = hT[ry];
        float wy0 = vy0 ? hy : 0.0f;
        float wy1 = vy1 ? (1.0f - hy) : 0.0f;
        float val = wy0 * (wxc0 * acc[0][reg] + wxc1 * acc[1][reg])
                  + wy1 * (wxc0 * acc[2][reg] + wxc1 * acc[3][reg]);
        float vv = val / ((wy0 + wy1) * sw + EPSF);
        ob[(size_t)ry * HH + cx] = __powf(fmaxf(vv, 0.0f) + EPSF, ig);
    }
}

extern "C" void kernel_launch(void* const* d_in, const int* in_sizes, int n_in,
                              void* d_out, int out_size, void* d_ws, size_t ws_size,
                              hipStream_t stream) {
    const float* x  = (const float*)d_in[0];
    const float* w1 = (const float*)d_in[1];
    const float* b1 = (const float*)d_in[2];
    const float* w2 = (const float*)d_in[3];
    const float* b2 = (const float*)d_in[4];
    const float* w3 = (const float*)d_in[5];
    const float* b3 = (const float*)d_in[6];
    const float* gp = (const float*)d_in[7];
    float* out = (float*)d_out;
    float* ws  = (float*)d_ws;

    int ntot = NB * NC * HH * HH;
    k_front<<<2048, 256, 0, stream>>>((const float4*)x, gp, (uint2*)(ws + XLIN_OFF),
                                      ntot / 4, w1, b1, w2, b2, w3, b3, ws);
    k_psf<<<NN * NC, 128, 0, stream>>>(ws);
    k_conv<<<NB * NC * 144, 256, 0, stream>>>(ws, gp, out);
}